// Round 17
// baseline (28.978 us; speedup 1.0000x reference)
//
#include <hip/hip_runtime.h>

#define L_ 512

typedef _Float16 v8h __attribute__((ext_vector_type(8)));
typedef __fp16   hf2 __attribute__((ext_vector_type(2)));
typedef float    v4f __attribute__((ext_vector_type(4)));

#define MFMA(a,b,c) __builtin_amdgcn_mfma_f32_16x16x32_f16(a,b,c,0,0,0)

// R12 champion + epilogue/prologue slimming (math identical):
//  (A) qm row-sums computed during staging from in-register wh -> qsums[512]
//      in LDS; epilogue qm = 4 broadcast ds_read_b32 (deletes ~256 VALU +
//      16 ds_read_b128 per thread).
//  (B) MLP weight/bias fragment loads hoisted BEFORE pass 1 (issue-early,
//      T14): their global latency hides under the attention compute.
//  (C) pass-1 fmax tree shaped for v_max3_f32 fusion (4 -> 2 insts).
// Math (verified r10/r11/r12): qfrag pre-scaled by C1; pass-2 QK C-operand =
// -C1*xmax; leaky dropped in pass 2; ones-MFMA denominator; cvt_pkrtz pack;
// pass-1/2 ping-pong register prefetch (r12).
// LDS layouts (verified r3+):
//   wfrag [st][sr+16c][j] = wrd[st*16+sr][8c+j]            (QK A-op, k=8g+j)
//   wtfrag[p][dt][(d&15)+16*((s>>2)&3)][(s&3)+4*((s>>4)&1)] = wrd[s][d]
//                                                          (PV A-op, k=4g+(j&3)+16*(j>>2))
// C/D map: col=lane&15, row=4*(lane>>4)+i (m89-verified).
__global__ __launch_bounds__(512, 2)
void attn_refine(const float* __restrict__ rgn, const float* __restrict__ wrd,
                 const float* __restrict__ Wsc, const float* __restrict__ bsc,
                 const float* __restrict__ W1,  const float* __restrict__ b1,
                 const float* __restrict__ W2,  const float* __restrict__ b2,
                 float* __restrict__ out)
{
    __shared__ __align__(16) _Float16 wfrag[32][64][8];       // 32 KB
    __shared__ __align__(16) _Float16 wtfrag[16][2][64][8];   // 32 KB
    __shared__ float qsums[L_];                               // 2 KB

    const int tid  = threadIdx.x;
    const int lane = tid & 63;
    const int wv   = tid >> 6;     // wave 0..7
    const int bb   = blockIdx.x;   // batch
    const int g    = lane >> 4;    // k-group 0..3
    const int lc   = lane & 15;    // col lane (q)

    // ---- staging: thread owns wrd row s = tid; row-sum -> qsums (A) ----
    {
        const v4f* wr4 = (const v4f*)(wrd + ((size_t)bb * L_ + tid) * 32);
        _Float16 wh[32];
        #pragma unroll
        for (int i = 0; i < 8; ++i) {
            v4f t = wr4[i];
            #pragma unroll
            for (int j = 0; j < 4; ++j) wh[4*i+j] = (_Float16)t[j];
        }
        const int st = tid >> 4, sr = tid & 15;
        #pragma unroll
        for (int c = 0; c < 4; ++c) {
            v8h pk;
            #pragma unroll
            for (int j = 0; j < 8; ++j) pk[j] = wh[8*c + j];
            *(v8h*)(&wfrag[st][sr + 16*c][0]) = pk;
        }
        const int pr   = tid >> 5;
        const int lgrp = 16 * ((tid >> 2) & 3);
        const int slot = (tid & 3) + 4 * ((tid >> 4) & 1);
        #pragma unroll
        for (int d = 0; d < 32; ++d)
            wtfrag[pr][d >> 4][(d & 15) + lgrp][slot] = wh[d];
        float rs = 0.f;
        #pragma unroll
        for (int d = 0; d < 32; d += 4)
            rs += ((float)wh[d] + (float)wh[d+1]) + ((float)wh[d+2] + (float)wh[d+3]);
        qsums[tid] = rs * 0.03125f;
    }

    const float C1 = 5.770780163555851f;    // 4*log2(e), folded into qfrag

    // ---- rgn B-fragments (registers), map (g,j) -> d = 8g+j; pre-scaled by C1 ----
    v8h qfrag[4];
    #pragma unroll
    for (int qt = 0; qt < 4; ++qt) {
        const v4f* rr = (const v4f*)(rgn + (((size_t)bb * L_) + wv*64 + qt*16 + lc) * 32 + g*8);
        v4f t0 = rr[0], t1 = rr[1];
        v8h f;
        #pragma unroll
        for (int j = 0; j < 4; ++j) { f[j] = (_Float16)(C1 * t0[j]); f[4+j] = (_Float16)(C1 * t1[j]); }
        qfrag[qt] = f;
    }

    // ---- (B) MLP weight/bias fragments loaded EARLY (latency hides under attn) ----
    const float* Wp[3] = {Wsc, W1, W2};
    const float* bp[3] = {bsc, b1, b2};
    v8h Wf[3][2];
    v4f bv[3][2];
    #pragma unroll
    for (int ly = 0; ly < 3; ++ly) {
        #pragma unroll
        for (int jt = 0; jt < 2; ++jt) {
            const v4f ta = *(const v4f*)(Wp[ly] + (jt*16 + lc)*32 + g*4);
            const v4f tb = *(const v4f*)(Wp[ly] + (jt*16 + lc)*32 + 16 + g*4);
            v8h f;
            #pragma unroll
            for (int j = 0; j < 4; ++j) { f[j] = (_Float16)ta[j]; f[4+j] = (_Float16)tb[j]; }
            Wf[ly][jt] = f;
            bv[ly][jt] = *(const v4f*)(bp[ly] + jt*16 + g*4);
        }
    }

    __syncthreads();

    const v4f vzero = {0.f, 0.f, 0.f, 0.f};

    // ---- pass 1: per-lane scaled-dot max, ping-pong prefetch (r12), max3 tree (C) ----
    float mraw[4] = {-3.0e38f, -3.0e38f, -3.0e38f, -3.0e38f};

#define P1LOAD(dst, base) do {                                              \
        _Pragma("unroll")                                                   \
        for (int i_ = 0; i_ < 4; ++i_)                                      \
            dst[i_] = *(const v8h*)(&wfrag[((base) + i_) & 31][lane][0]);   \
    } while (0)
#define P1COMP(gr) do {                                                     \
        _Pragma("unroll")                                                   \
        for (int i_ = 0; i_ < 4; ++i_) {                                    \
            _Pragma("unroll")                                               \
            for (int qt_ = 0; qt_ < 4; ++qt_) {                             \
                v4f s_ = MFMA(gr[i_], qfrag[qt_], vzero);                   \
                float r_ = fmaxf(fmaxf(s_[0], s_[1]), s_[2]);               \
                mraw[qt_] = fmaxf(fmaxf(r_, s_[3]), mraw[qt_]);             \
            }                                                               \
        }                                                                   \
    } while (0)

    {
        v8h gA[4], gB[4];
        P1LOAD(gA, 0);
        #pragma unroll 1
        for (int stb = 0; stb < 32; stb += 8) {
            P1LOAD(gB, stb + 4);
            P1COMP(gA);
            P1LOAD(gA, (stb + 8) & 31);
            P1COMP(gB);
        }
    }

    v4f nm4[4];   // broadcast(-C1*xmax) per q-tile, fed as MFMA C-operand
    #pragma unroll
    for (int qt = 0; qt < 4; ++qt) {
        float v = mraw[qt];
        v = fmaxf(v, __shfl_xor(v, 16));
        v = fmaxf(v, __shfl_xor(v, 32));
        nm4[qt] = (v4f){-v, -v, -v, -v};
    }

    // ---- pass 2: z2 from MFMA C-op; P = exp2; denom via ones-MFMA; ping-pong ----
    const v8h ones = {(_Float16)1.f, (_Float16)1.f, (_Float16)1.f, (_Float16)1.f,
                      (_Float16)1.f, (_Float16)1.f, (_Float16)1.f, (_Float16)1.f};
    v4f acc[4][2], accL[4];
    #pragma unroll
    for (int qt = 0; qt < 4; ++qt) { acc[qt][0] = vzero; acc[qt][1] = vzero; accL[qt] = vzero; }

#define P2LOAD(dst, p) do {                                                 \
        dst[0] = *(const v8h*)(&wfrag[2*((p)&15)    ][lane][0]);            \
        dst[1] = *(const v8h*)(&wfrag[2*((p)&15) + 1][lane][0]);            \
        dst[2] = *(const v8h*)(&wtfrag[(p)&15][0][lane][0]);                \
        dst[3] = *(const v8h*)(&wtfrag[(p)&15][1][lane][0]);                \
    } while (0)
#define P2COMP(fr) do {                                                     \
        _Pragma("unroll")                                                   \
        for (int qt_ = 0; qt_ < 4; ++qt_) {                                 \
            v4f sa_ = MFMA(fr[0], qfrag[qt_], nm4[qt_]);                    \
            v4f sb_ = MFMA(fr[1], qfrag[qt_], nm4[qt_]);                    \
            union { hf2 h[4]; v8h v; } u_;                                  \
            u_.h[0] = __builtin_amdgcn_cvt_pkrtz(                           \
                __builtin_amdgcn_exp2f(sa_[0]), __builtin_amdgcn_exp2f(sa_[1])); \
            u_.h[1] = __builtin_amdgcn_cvt_pkrtz(                           \
                __builtin_amdgcn_exp2f(sa_[2]), __builtin_amdgcn_exp2f(sa_[3])); \
            u_.h[2] = __builtin_amdgcn_cvt_pkrtz(                           \
                __builtin_amdgcn_exp2f(sb_[0]), __builtin_amdgcn_exp2f(sb_[1])); \
            u_.h[3] = __builtin_amdgcn_cvt_pkrtz(                           \
                __builtin_amdgcn_exp2f(sb_[2]), __builtin_amdgcn_exp2f(sb_[3])); \
            v8h pb_ = u_.v;                                                 \
            acc[qt_][0] = MFMA(fr[2], pb_, acc[qt_][0]);                    \
            acc[qt_][1] = MFMA(fr[3], pb_, acc[qt_][1]);                    \
            accL[qt_]   = MFMA(ones, pb_, accL[qt_]);                       \
        }                                                                   \
    } while (0)

    {
        v8h frA[4], frB[4];
        P2LOAD(frA, 0);
        #pragma unroll 1
        for (int p = 0; p < 16; p += 2) {
            P2LOAD(frB, p + 1);
            P2COMP(frA);
            P2LOAD(frA, p + 2);
            P2COMP(frB);
        }
    }

    // ---- denominators (uniform per column: no cross-lane reduce needed) ----
    float inv[4];
    #pragma unroll
    for (int qt = 0; qt < 4; ++qt) inv[qt] = 1.0f / accL[qt][0];

    // ---- qm from qsums (A): 4 broadcast ds_read_b32 ----
    float qm[4];
    #pragma unroll
    for (int qt = 0; qt < 4; ++qt) qm[qt] = qsums[wv*64 + qt*16 + lc];

    // ---- MLP (all matmuls as MFMA, transposed form: y^T = W * x^T) ----
    const float CT = 2.885390081777927f;   // 2*log2(e)
    #pragma unroll
    for (int qt = 0; qt < 4; ++qt) {
        v8h xb;
        #pragma unroll
        for (int i = 0; i < 4; ++i) {
            xb[i]   = (_Float16)(acc[qt][0][i] * inv[qt]);
            xb[4+i] = (_Float16)(acc[qt][1][i] * inv[qt]);
        }
        v4f y0 = MFMA(Wf[0][0], xb, vzero);
        v4f y1 = MFMA(Wf[0][1], xb, vzero);
        v8h sb;
        #pragma unroll
        for (int i = 0; i < 4; ++i) {
            float t0 = y0[i] + bv[0][0][i];
            float t1 = y1[i] + bv[0][1][i];
            float e0 = __builtin_amdgcn_exp2f(CT * t0);
            float e1 = __builtin_amdgcn_exp2f(CT * t1);
            sb[i]   = (_Float16)(1.f - 2.f / (e0 + 1.f));   // tanh
            sb[4+i] = (_Float16)(1.f - 2.f / (e1 + 1.f));
        }
        v4f z0 = MFMA(Wf[1][0], sb, vzero);
        v4f z1 = MFMA(Wf[1][1], sb, vzero);
        v8h hb;
        #pragma unroll
        for (int i = 0; i < 4; ++i) {
            hb[i]   = (_Float16)fmaxf(fmaf(qm[qt], z0[i], bv[1][0][i]), 0.f);
            hb[4+i] = (_Float16)fmaxf(fmaf(qm[qt], z1[i], bv[1][1][i]), 0.f);
        }
        v4f r0 = MFMA(Wf[2][0], hb, vzero);
        v4f r1 = MFMA(Wf[2][1], hb, vzero);
        v4f o0, o1;
        #pragma unroll
        for (int i = 0; i < 4; ++i) {
            o0[i] = r0[i] + bv[2][0][i] + qm[qt];
            o1[i] = r1[i] + bv[2][1][i] + qm[qt];
        }
        float* ob = out + ((size_t)bb * L_ + wv*64 + qt*16 + lc) * 32;
        *(v4f*)(ob + g*4)      = o0;
        *(v4f*)(ob + 16 + g*4) = o1;
    }
}

extern "C" void kernel_launch(void* const* d_in, const int* in_sizes, int n_in,
                              void* d_out, int out_size, void* d_ws, size_t ws_size,
                              hipStream_t stream) {
    const float* rgn = (const float*)d_in[0];
    const float* wrd = (const float*)d_in[1];
    const float* Wsc = (const float*)d_in[2];
    const float* bsc = (const float*)d_in[3];
    const float* W1  = (const float*)d_in[4];
    const float* b1  = (const float*)d_in[5];
    const float* W2  = (const float*)d_in[6];
    const float* b2  = (const float*)d_in[7];
    float* out = (float*)d_out;

    attn_refine<<<dim3(256), dim3(512), 0, stream>>>(rgn, wrd, Wsc, bsc, W1, b1, W2, b2, out);
}

// Round 18
// 28.245 us; speedup vs baseline: 1.0260x; 1.0260x over previous
//
#include <hip/hip_runtime.h>

#define L_ 512

typedef _Float16 v8h __attribute__((ext_vector_type(8)));
typedef __fp16   hf2 __attribute__((ext_vector_type(2)));
typedef float    v4f __attribute__((ext_vector_type(4)));

#define MFMA(a,b,c) __builtin_amdgcn_mfma_f32_16x16x32_f16(a,b,c,0,0,0)

// FINAL (R12 champion, 28.2 us): grid 256 = 1 block/batch, 512 thr = 8 waves,
// wave owns 64 q (qt=4), two-pass branch-free softmax, both passes ping-pong
// register-prefetched. Math: qfrag pre-scaled by C1=4*log2(e); pass-2 QK MFMA
// C-operand = -C1*xmax (z2 emitted directly); leaky-ReLU dropped in pass 2
// (negative logits round to the same ~0 f16 P); denominator via ones-MFMA;
// P packed via v_cvt_pkrtz_f16_f32. LDS layouts (verified r3+):
//   wfrag [st][sr+16c][j] = wrd[st*16+sr][8c+j]            (QK A-op, k=8g+j)
//   wtfrag[p][dt][(d&15)+16*((s>>2)&3)][(s&3)+4*((s>>4)&1)] = wrd[s][d]
//                                                          (PV A-op, k=4g+(j&3)+16*(j>>2))
// C/D map: col=lane&15, row=4*(lane>>4)+i (m89-verified).
// Plateau evidence (r12-r17): 28.2-29.0 us across 5 structural variants; all
// pipe utilizations <=35%; TLP, deeper pipelining, register residency, and
// issue-count cuts all exhausted at source level.
__global__ __launch_bounds__(512, 2)
void attn_refine(const float* __restrict__ rgn, const float* __restrict__ wrd,
                 const float* __restrict__ Wsc, const float* __restrict__ bsc,
                 const float* __restrict__ W1,  const float* __restrict__ b1,
                 const float* __restrict__ W2,  const float* __restrict__ b2,
                 float* __restrict__ out)
{
    __shared__ __align__(16) _Float16 wfrag[32][64][8];       // 32 KB
    __shared__ __align__(16) _Float16 wtfrag[16][2][64][8];   // 32 KB

    const int tid  = threadIdx.x;
    const int lane = tid & 63;
    const int wv   = tid >> 6;     // wave 0..7
    const int bb   = blockIdx.x;   // batch
    const int g    = lane >> 4;    // k-group 0..3
    const int lc   = lane & 15;    // col lane (q)

    // ---- staging: thread owns wrd row s = tid ----
    {
        const v4f* wr4 = (const v4f*)(wrd + ((size_t)bb * L_ + tid) * 32);
        _Float16 wh[32];
        #pragma unroll
        for (int i = 0; i < 8; ++i) {
            v4f t = wr4[i];
            #pragma unroll
            for (int j = 0; j < 4; ++j) wh[4*i+j] = (_Float16)t[j];
        }
        const int st = tid >> 4, sr = tid & 15;
        #pragma unroll
        for (int c = 0; c < 4; ++c) {
            v8h pk;
            #pragma unroll
            for (int j = 0; j < 8; ++j) pk[j] = wh[8*c + j];
            *(v8h*)(&wfrag[st][sr + 16*c][0]) = pk;
        }
        const int pr   = tid >> 5;
        const int lgrp = 16 * ((tid >> 2) & 3);
        const int slot = (tid & 3) + 4 * ((tid >> 4) & 1);
        #pragma unroll
        for (int d = 0; d < 32; ++d)
            wtfrag[pr][d >> 4][(d & 15) + lgrp][slot] = wh[d];
    }

    const float C1 = 5.770780163555851f;    // 4*log2(e), folded into qfrag

    // ---- rgn B-fragments (registers), map (g,j) -> d = 8g+j; pre-scaled by C1 ----
    v8h qfrag[4];
    #pragma unroll
    for (int qt = 0; qt < 4; ++qt) {
        const v4f* rr = (const v4f*)(rgn + (((size_t)bb * L_) + wv*64 + qt*16 + lc) * 32 + g*8);
        v4f t0 = rr[0], t1 = rr[1];
        v8h f;
        #pragma unroll
        for (int j = 0; j < 4; ++j) { f[j] = (_Float16)(C1 * t0[j]); f[4+j] = (_Float16)(C1 * t1[j]); }
        qfrag[qt] = f;
    }

    __syncthreads();

    const v4f vzero = {0.f, 0.f, 0.f, 0.f};

    // ---- pass 1: per-lane scaled-dot max, ping-pong prefetch in groups of 4 ----
    float mraw[4] = {-3.0e38f, -3.0e38f, -3.0e38f, -3.0e38f};

#define P1LOAD(dst, base) do {                                              \
        _Pragma("unroll")                                                   \
        for (int i_ = 0; i_ < 4; ++i_)                                      \
            dst[i_] = *(const v8h*)(&wfrag[((base) + i_) & 31][lane][0]);   \
    } while (0)
#define P1COMP(gr) do {                                                     \
        _Pragma("unroll")                                                   \
        for (int i_ = 0; i_ < 4; ++i_) {                                    \
            _Pragma("unroll")                                               \
            for (int qt_ = 0; qt_ < 4; ++qt_) {                             \
                v4f s_ = MFMA(gr[i_], qfrag[qt_], vzero);                   \
                mraw[qt_] = fmaxf(fmaxf(s_[0], s_[1]),                      \
                                  fmaxf(fmaxf(s_[2], s_[3]), mraw[qt_]));   \
            }                                                               \
        }                                                                   \
    } while (0)

    {
        v8h gA[4], gB[4];
        P1LOAD(gA, 0);
        #pragma unroll 1
        for (int stb = 0; stb < 32; stb += 8) {
            P1LOAD(gB, stb + 4);
            P1COMP(gA);
            P1LOAD(gA, (stb + 8) & 31);
            P1COMP(gB);
        }
    }

    v4f nm4[4];   // broadcast(-C1*xmax) per q-tile, fed as MFMA C-operand
    #pragma unroll
    for (int qt = 0; qt < 4; ++qt) {
        float v = mraw[qt];
        v = fmaxf(v, __shfl_xor(v, 16));
        v = fmaxf(v, __shfl_xor(v, 32));
        nm4[qt] = (v4f){-v, -v, -v, -v};
    }

    // ---- pass 2: z2 from MFMA C-op; P = exp2; denom via ones-MFMA; ping-pong ----
    const v8h ones = {(_Float16)1.f, (_Float16)1.f, (_Float16)1.f, (_Float16)1.f,
                      (_Float16)1.f, (_Float16)1.f, (_Float16)1.f, (_Float16)1.f};
    v4f acc[4][2], accL[4];
    #pragma unroll
    for (int qt = 0; qt < 4; ++qt) { acc[qt][0] = vzero; acc[qt][1] = vzero; accL[qt] = vzero; }

#define P2LOAD(dst, p) do {                                                 \
        dst[0] = *(const v8h*)(&wfrag[2*((p)&15)    ][lane][0]);            \
        dst[1] = *(const v8h*)(&wfrag[2*((p)&15) + 1][lane][0]);            \
        dst[2] = *(const v8h*)(&wtfrag[(p)&15][0][lane][0]);                \
        dst[3] = *(const v8h*)(&wtfrag[(p)&15][1][lane][0]);                \
    } while (0)
#define P2COMP(fr) do {                                                     \
        _Pragma("unroll")                                                   \
        for (int qt_ = 0; qt_ < 4; ++qt_) {                                 \
            v4f sa_ = MFMA(fr[0], qfrag[qt_], nm4[qt_]);                    \
            v4f sb_ = MFMA(fr[1], qfrag[qt_], nm4[qt_]);                    \
            union { hf2 h[4]; v8h v; } u_;                                  \
            u_.h[0] = __builtin_amdgcn_cvt_pkrtz(                           \
                __builtin_amdgcn_exp2f(sa_[0]), __builtin_amdgcn_exp2f(sa_[1])); \
            u_.h[1] = __builtin_amdgcn_cvt_pkrtz(                           \
                __builtin_amdgcn_exp2f(sa_[2]), __builtin_amdgcn_exp2f(sa_[3])); \
            u_.h[2] = __builtin_amdgcn_cvt_pkrtz(                           \
                __builtin_amdgcn_exp2f(sb_[0]), __builtin_amdgcn_exp2f(sb_[1])); \
            u_.h[3] = __builtin_amdgcn_cvt_pkrtz(                           \
                __builtin_amdgcn_exp2f(sb_[2]), __builtin_amdgcn_exp2f(sb_[3])); \
            v8h pb_ = u_.v;                                                 \
            acc[qt_][0] = MFMA(fr[2], pb_, acc[qt_][0]);                    \
            acc[qt_][1] = MFMA(fr[3], pb_, acc[qt_][1]);                    \
            accL[qt_]   = MFMA(ones, pb_, accL[qt_]);                       \
        }                                                                   \
    } while (0)

    {
        v8h frA[4], frB[4];
        P2LOAD(frA, 0);
        #pragma unroll 1
        for (int p = 0; p < 16; p += 2) {
            P2LOAD(frB, p + 1);
            P2COMP(frA);
            P2LOAD(frA, p + 2);
            P2COMP(frB);
        }
    }

    // ---- denominators (uniform per column: no cross-lane reduce needed) ----
    float inv[4];
    #pragma unroll
    for (int qt = 0; qt < 4; ++qt) inv[qt] = 1.0f / accL[qt][0];

    // ---- qm (row mean of wrd, from f16 frags) ----
    float qm[4];
    #pragma unroll
    for (int qt = 0; qt < 4; ++qt) {
        float ssum = 0.f;
        #pragma unroll
        for (int c = 0; c < 4; ++c) {
            v8h r = *(const v8h*)(&wfrag[wv*4 + qt][lc + 16*c][0]);
            #pragma unroll
            for (int j = 0; j < 8; ++j) ssum += (float)r[j];
        }
        qm[qt] = ssum * 0.03125f;
    }

    // ---- MLP weight/bias fragments (registers) ----
    const float* Wp[3] = {Wsc, W1, W2};
    const float* bp[3] = {bsc, b1, b2};
    v8h Wf[3][2];
    v4f bv[3][2];
    #pragma unroll
    for (int ly = 0; ly < 3; ++ly) {
        #pragma unroll
        for (int jt = 0; jt < 2; ++jt) {
            const v4f ta = *(const v4f*)(Wp[ly] + (jt*16 + lc)*32 + g*4);
            const v4f tb = *(const v4f*)(Wp[ly] + (jt*16 + lc)*32 + 16 + g*4);
            v8h f;
            #pragma unroll
            for (int j = 0; j < 4; ++j) { f[j] = (_Float16)ta[j]; f[4+j] = (_Float16)tb[j]; }
            Wf[ly][jt] = f;
            bv[ly][jt] = *(const v4f*)(bp[ly] + jt*16 + g*4);
        }
    }

    // ---- MLP (all matmuls as MFMA, transposed form: y^T = W * x^T) ----
    const float CT = 2.885390081777927f;   // 2*log2(e)
    #pragma unroll
    for (int qt = 0; qt < 4; ++qt) {
        v8h xb;
        #pragma unroll
        for (int i = 0; i < 4; ++i) {
            xb[i]   = (_Float16)(acc[qt][0][i] * inv[qt]);
            xb[4+i] = (_Float16)(acc[qt][1][i] * inv[qt]);
        }
        v4f y0 = MFMA(Wf[0][0], xb, vzero);
        v4f y1 = MFMA(Wf[0][1], xb, vzero);
        v8h sb;
        #pragma unroll
        for (int i = 0; i < 4; ++i) {
            float t0 = y0[i] + bv[0][0][i];
            float t1 = y1[i] + bv[0][1][i];
            float e0 = __builtin_amdgcn_exp2f(CT * t0);
            float e1 = __builtin_amdgcn_exp2f(CT * t1);
            sb[i]   = (_Float16)(1.f - 2.f / (e0 + 1.f));   // tanh
            sb[4+i] = (_Float16)(1.f - 2.f / (e1 + 1.f));
        }
        v4f z0 = MFMA(Wf[1][0], sb, vzero);
        v4f z1 = MFMA(Wf[1][1], sb, vzero);
        v8h hb;
        #pragma unroll
        for (int i = 0; i < 4; ++i) {
            hb[i]   = (_Float16)fmaxf(fmaf(qm[qt], z0[i], bv[1][0][i]), 0.f);
            hb[4+i] = (_Float16)fmaxf(fmaf(qm[qt], z1[i], bv[1][1][i]), 0.f);
        }
        v4f r0 = MFMA(Wf[2][0], hb, vzero);
        v4f r1 = MFMA(Wf[2][1], hb, vzero);
        v4f o0, o1;
        #pragma unroll
        for (int i = 0; i < 4; ++i) {
            o0[i] = r0[i] + bv[2][0][i] + qm[qt];
            o1[i] = r1[i] + bv[2][1][i] + qm[qt];
        }
        float* ob = out + ((size_t)bb * L_ + wv*64 + qt*16 + lc) * 32;
        *(v4f*)(ob + g*4)      = o0;
        *(v4f*)(ob + 16 + g*4) = o1;
    }
}

extern "C" void kernel_launch(void* const* d_in, const int* in_sizes, int n_in,
                              void* d_out, int out_size, void* d_ws, size_t ws_size,
                              hipStream_t stream) {
    const float* rgn = (const float*)d_in[0];
    const float* wrd = (const float*)d_in[1];
    const float* Wsc = (const float*)d_in[2];
    const float* bsc = (const float*)d_in[3];
    const float* W1  = (const float*)d_in[4];
    const float* b1  = (const float*)d_in[5];
    const float* W2  = (const float*)d_in[6];
    const float* b2  = (const float*)d_in[7];
    float* out = (float*)d_out;

    attn_refine<<<dim3(256), dim3(512), 0, stream>>>(rgn, wrd, Wsc, bsc, W1, b1, W2, b2, out);
}